// Round 1
// baseline (2125.640 us; speedup 1.0000x reference)
//
#include <hip/hip_runtime.h>
#include <cstddef>

namespace {
constexpr int kThreads = 256;
constexpr int kRows = 16;        // batch rows per block
constexpr int kH = 128;
constexpr int kG = 512;          // 4*H
constexpr int kTEnc = 50;
constexpr int kTDec = 60;
constexpr int kDIn = 6;
constexpr int kDOut = 2;
constexpr int kBTot = 8192;
}

__device__ __forceinline__ float sigf(float x) { return 1.0f / (1.0f + __expf(-x)); }
// tanh(x) = 1 - 2/(exp(2x)+1)  (saturates correctly at +/-1 for large |x|)
__device__ __forceinline__ float tanhf_fast(float x) { return 1.0f - 2.0f / (__expf(2.0f * x) + 1.0f); }

// Transpose enc/dec Whh (512x128 row-major) into k-major, 4-k-interleaved layout:
// WT4[kb][j][kk] = Whh[j][kb*4+kk]  (kb in [0,32), j in [0,512), kk in [0,4))
// so the main loop reads float4 {Whh[j][4kb..4kb+3]} at WT4 + kb*2048 + j*4,
// perfectly coalesced across lanes (consecutive j).
__global__ void lstm_prep(const float* __restrict__ encWhh,
                          const float* __restrict__ decWhh,
                          float* __restrict__ ws) {
    int idx = blockIdx.x * kThreads + threadIdx.x;  // 0..131071
    const float* src = encWhh;
    float* dst = ws;
    if (idx >= 65536) { src = decWhh; dst = ws + 65536; idx -= 65536; }
    const int j = idx >> 7;       // 0..511
    const int k = idx & 127;      // 0..127
    dst[(k >> 2) * (kG * 4) + j * 4 + (k & 3)] = src[j * kH + k];
}

// acc[q][g] += sum_k h[2q+rh][k] * Whh[m+128g][k]
__device__ __forceinline__ void gate_hh(float acc[8][4],
                                        const float (*h)[kH],
                                        const float* __restrict__ WT4,
                                        int m, int rh)
{
    #pragma unroll 4
    for (int kb = 0; kb < kH / 4; kb++) {
        const float4 w0 = *(const float4*)(WT4 + kb * 2048 + (m)       * 4);
        const float4 w1 = *(const float4*)(WT4 + kb * 2048 + (m + 128) * 4);
        const float4 w2 = *(const float4*)(WT4 + kb * 2048 + (m + 256) * 4);
        const float4 w3 = *(const float4*)(WT4 + kb * 2048 + (m + 384) * 4);
        #pragma unroll
        for (int q = 0; q < 8; q++) {
            const float4 hv = *(const float4*)(&h[2 * q + rh][kb * 4]);  // uniform addr -> LDS broadcast
            acc[q][0] += hv.x * w0.x + hv.y * w0.y + hv.z * w0.z + hv.w * w0.w;
            acc[q][1] += hv.x * w1.x + hv.y * w1.y + hv.z * w1.z + hv.w * w1.w;
            acc[q][2] += hv.x * w2.x + hv.y * w2.y + hv.z * w2.z + hv.w * w2.w;
            acc[q][3] += hv.x * w3.x + hv.y * w3.y + hv.z * w3.z + hv.w * w3.w;
        }
    }
}

__device__ __forceinline__ void cell_update(float acc[8][4], float c[8],
                                            float (*hnew)[kH], int m, int rh)
{
    #pragma unroll
    for (int q = 0; q < 8; q++) {
        const float iv = sigf(acc[q][0]);
        const float fv = sigf(acc[q][1]);
        const float gv = tanhf_fast(acc[q][2]);
        const float ov = sigf(acc[q][3]);
        c[q] = fv * c[q] + iv * gv;
        hnew[2 * q + rh][m] = ov * tanhf_fast(c[q]);
    }
}

__global__ __launch_bounds__(kThreads, 2) void lstm_main(
    const float* __restrict__ x,
    const float* __restrict__ encWih,
    const float* __restrict__ encbih,
    const float* __restrict__ encbhh,
    const float* __restrict__ decWih,
    const float* __restrict__ decbih,
    const float* __restrict__ decbhh,
    const float* __restrict__ projW,
    const float* __restrict__ projb,
    const float* __restrict__ ws,
    float* __restrict__ out)
{
    __shared__ float xs[kRows][kTEnc * kDIn];   // per-row input sequence
    __shared__ float h_buf[2][kRows][kH];       // ping-pong h
    __shared__ float wixT[kDIn][kG];            // enc Wih^T
    __shared__ float wdxT[kDOut][kG];           // dec Wih^T
    __shared__ float encb_s[kG];
    __shared__ float decb_s[kG];
    __shared__ float pw_s[kDOut][kH];
    __shared__ float pb_s[kDOut];
    __shared__ float inp_s[kRows][kDOut];

    const int tid = threadIdx.x;
    const int m = tid & (kH - 1);     // gate-lane index 0..127
    const int rh = tid >> 7;          // row parity 0/1
    const int rowBase = blockIdx.x * kRows;

    // ---- one-time staging ----
    for (int idx = tid; idx < kRows * kTEnc * kDIn; idx += kThreads) {
        int r = idx / (kTEnc * kDIn);
        int p = idx - r * (kTEnc * kDIn);
        xs[r][p] = x[(size_t)(rowBase + r) * (kTEnc * kDIn) + p];
    }
    for (int idx = tid; idx < kG * kDIn; idx += kThreads) {
        int j = idx / kDIn;
        int k = idx - j * kDIn;
        wixT[k][j] = encWih[idx];
    }
    for (int idx = tid; idx < kG * kDOut; idx += kThreads) {
        wdxT[idx & 1][idx >> 1] = decWih[idx];
    }
    for (int idx = tid; idx < kG; idx += kThreads) {
        encb_s[idx] = encbih[idx] + encbhh[idx];
        decb_s[idx] = decbih[idx] + decbhh[idx];
    }
    for (int idx = tid; idx < kDOut * kH; idx += kThreads)
        pw_s[idx >> 7][idx & (kH - 1)] = projW[idx];
    if (tid < kDOut) pb_s[tid] = projb[tid];
    for (int idx = tid; idx < kRows * kH; idx += kThreads)
        (&h_buf[0][0][0])[idx] = 0.0f;          // h0 = 0
    __syncthreads();

    float c[8];
    #pragma unroll
    for (int q = 0; q < 8; q++) c[q] = 0.0f;    // c0 = 0

    const float* encWT4 = ws;
    const float* decWT4 = ws + 65536;
    int cur = 0;

    // ---- encoder: 50 steps ----
    for (int t = 0; t < kTEnc; t++) {
        float acc[8][4];
        const float b0 = encb_s[m], b1 = encb_s[m + 128], b2 = encb_s[m + 256], b3 = encb_s[m + 384];
        #pragma unroll
        for (int q = 0; q < 8; q++) { acc[q][0] = b0; acc[q][1] = b1; acc[q][2] = b2; acc[q][3] = b3; }
        #pragma unroll
        for (int k = 0; k < kDIn; k++) {
            const float w0 = wixT[k][m], w1 = wixT[k][m + 128], w2 = wixT[k][m + 256], w3 = wixT[k][m + 384];
            #pragma unroll
            for (int q = 0; q < 8; q++) {
                const float xv = xs[2 * q + rh][t * kDIn + k];
                acc[q][0] += xv * w0; acc[q][1] += xv * w1; acc[q][2] += xv * w2; acc[q][3] += xv * w3;
            }
        }
        gate_hh(acc, h_buf[cur], encWT4, m, rh);
        cell_update(acc, c, h_buf[cur ^ 1], m, rh);
        __syncthreads();
        cur ^= 1;
    }

    // decoder initial input = x[:, -1, :2]
    if (tid < kRows * kDOut) {
        int r = tid >> 1, j = tid & 1;
        inp_s[r][j] = xs[r][(kTEnc - 1) * kDIn + j];
    }
    __syncthreads();

    // ---- decoder: 60 steps ----
    for (int t = 0; t < kTDec; t++) {
        float acc[8][4];
        const float b0 = decb_s[m], b1 = decb_s[m + 128], b2 = decb_s[m + 256], b3 = decb_s[m + 384];
        #pragma unroll
        for (int q = 0; q < 8; q++) { acc[q][0] = b0; acc[q][1] = b1; acc[q][2] = b2; acc[q][3] = b3; }
        #pragma unroll
        for (int k = 0; k < kDOut; k++) {
            const float w0 = wdxT[k][m], w1 = wdxT[k][m + 128], w2 = wdxT[k][m + 256], w3 = wdxT[k][m + 384];
            #pragma unroll
            for (int q = 0; q < 8; q++) {
                const float xv = inp_s[2 * q + rh][k];
                acc[q][0] += xv * w0; acc[q][1] += xv * w1; acc[q][2] += xv * w2; acc[q][3] += xv * w3;
            }
        }
        gate_hh(acc, h_buf[cur], decWT4, m, rh);
        cell_update(acc, c, h_buf[cur ^ 1], m, rh);
        __syncthreads();
        cur ^= 1;   // h_buf[cur] now holds the new h

        // pred = h_new @ proj_W.T + proj_b ; feed back as next input
        if (tid < kRows * kDOut) {
            int r = tid >> 1, j = tid & 1;
            float s = pb_s[j];
            const float* hr = &h_buf[cur][r][0];
            const float* pwj = &pw_s[j][0];
            #pragma unroll 8
            for (int k2 = 0; k2 < kH; k2++) s += hr[k2] * pwj[k2];
            out[(size_t)(rowBase + r) * (kTDec * kDOut) + t * kDOut + j] = s;
            inp_s[r][j] = s;
        }
        __syncthreads();
    }
}

extern "C" void kernel_launch(void* const* d_in, const int* in_sizes, int n_in,
                              void* d_out, int out_size, void* d_ws, size_t ws_size,
                              hipStream_t stream) {
    const float* x      = (const float*)d_in[0];
    const float* encWih = (const float*)d_in[1];
    const float* encWhh = (const float*)d_in[2];
    const float* encbih = (const float*)d_in[3];
    const float* encbhh = (const float*)d_in[4];
    const float* decWih = (const float*)d_in[5];
    const float* decWhh = (const float*)d_in[6];
    const float* decbih = (const float*)d_in[7];
    const float* decbhh = (const float*)d_in[8];
    const float* projW  = (const float*)d_in[9];
    const float* projb  = (const float*)d_in[10];
    float* ws  = (float*)d_ws;
    float* out = (float*)d_out;

    // transpose/interleave the two 512x128 recurrent matrices into ws (512 KB)
    lstm_prep<<<512, kThreads, 0, stream>>>(encWhh, decWhh, ws);
    // 512 blocks x 256 threads, 16 rows each; whole grid co-resident (2 blocks/CU)
    lstm_main<<<kBTot / kRows, kThreads, 0, stream>>>(
        x, encWih, encbih, encbhh, decWih, decbih, decbhh, projW, projb, ws, out);
}

// Round 2
// 420.608 us; speedup vs baseline: 5.0537x; 5.0537x over previous
//
#include <hip/hip_runtime.h>
#include <cstddef>

typedef __attribute__((ext_vector_type(8))) _Float16 half8;
typedef __attribute__((ext_vector_type(4))) _Float16 half4;
typedef __attribute__((ext_vector_type(4))) float floatx4;

namespace {
constexpr int kH = 128;
constexpr int kG = 512;          // 4*H
constexpr int kTEnc = 50;
constexpr int kTDec = 60;
constexpr int kRows = 32;        // batch rows per block
constexpr int kThreads = 512;    // 8 waves
constexpr int kWfHalves = 2 * 32 * 5 * 64 * 8;   // W' frags: [mat][gtile][kc][lane][j]
}

__device__ __forceinline__ float sigf(float x) { return 1.0f / (1.0f + __expf(-x)); }
__device__ __forceinline__ float tanhf_fast(float x) { return 1.0f - 2.0f / (__expf(2.0f * x) + 1.0f); }

// Pack W' = [Whh | Wih | pad] (512 x 160) as fp16 MFMA A-fragments, plus fused biases.
// Fragment element (mat, gtile, kc, lane, j) holds W'[gtile*16 + (lane&15)][kc*32 + (lane>>4)*8 + j].
// The main kernel uses the SAME (lane,j)->k map for B (h/x) fragments, so the contraction is
// correct regardless of the hardware's internal k ordering (dot products are permutation-invariant).
__global__ void lstm_prep(const float* __restrict__ encWhh, const float* __restrict__ encWih,
                          const float* __restrict__ decWhh, const float* __restrict__ decWih,
                          const float* __restrict__ encbih, const float* __restrict__ encbhh,
                          const float* __restrict__ decbih, const float* __restrict__ decbhh,
                          _Float16* __restrict__ wf, float* __restrict__ bias_out) {
    int idx = blockIdx.x * 256 + threadIdx.x;
    if (idx < 2 * 32 * 5 * 64) {
        const int lane = idx & 63;
        const int kc   = (idx >> 6) % 5;
        const int gt   = (idx / 320) & 31;
        const int mat  = idx / 10240;
        const float* Whh = mat ? decWhh : encWhh;
        const float* Wih = mat ? decWih : encWih;
        const int din = mat ? 2 : 6;
        const int g = gt * 16 + (lane & 15);
        _Float16 vals[8];
        #pragma unroll
        for (int j = 0; j < 8; j++) {
            int k = kc * 32 + (lane >> 4) * 8 + j;
            float v = 0.0f;
            if (k < kH) v = Whh[g * kH + k];
            else if (k - kH < din) v = Wih[g * din + (k - kH)];
            vals[j] = (_Float16)v;
        }
        *(half8*)(wf + (size_t)idx * 8) = *(half8*)vals;
    }
    if (idx < 2 * kG) {
        int mat = idx >> 9, g = idx & (kG - 1);
        bias_out[idx] = mat ? (decbih[g] + decbhh[g]) : (encbih[g] + encbhh[g]);
    }
}

__global__ __launch_bounds__(kThreads, 2) void lstm_main(
    const float* __restrict__ x,
    const _Float16* __restrict__ wf,
    const float* __restrict__ biases,
    const float* __restrict__ projW,
    const float* __restrict__ projb,
    float* __restrict__ out)
{
    __shared__ alignas(16) _Float16 xsH[kTEnc][32][8];   // x hi, zero-padded d=6,7
    __shared__ alignas(16) _Float16 xsL[kTEnc][32][8];   // x lo
    __shared__ alignas(16) _Float16 hH[2][32][kH];       // h hi (XOR-swizzled), ping-pong
    __shared__ alignas(16) _Float16 hL[2][32][kH];       // h lo
    __shared__ float inp_s[32][2];
    __shared__ float partial[32][2][8];

    const int tid  = threadIdx.x;
    const int lane = tid & 63;
    const int wv   = tid >> 6;        // wave 0..7: owns gate-cols [16wv,16wv+16) of each gate
    const int l15  = lane & 15;
    const int l4   = lane >> 4;
    const int rowBase = blockIdx.x * kRows;

    // ---- stage x (split to f16 hi/lo, t-major for conflict-free fragment reads) ----
    for (int i = tid; i < kTEnc * 32 * 8; i += kThreads) {
        int d = i & 7;
        int r = (i >> 3) & 31;
        int t = i >> 8;
        float v = (d < 6) ? x[(size_t)(rowBase + r) * (kTEnc * 6) + t * 6 + d] : 0.0f;
        _Float16 hi = (_Float16)v;
        xsH[t][r][d] = hi;
        xsL[t][r][d] = (_Float16)(v - (float)hi);
    }
    for (int i = tid; i < 32 * kH; i += kThreads) {
        (&hH[0][0][0])[i] = (_Float16)0.0f;
        (&hL[0][0][0])[i] = (_Float16)0.0f;
    }

    // ---- per-wave register-resident weights / biases / proj slice ----
    half8  wfr[4][5];   // [gate-type][kchunk], 80 VGPR
    floatx4 bs4[4];     // bias for acc rows
    floatx4 pwr[2];     // projW[j] at this lane's 4 cols
    #pragma unroll
    for (int j = 0; j < 2; j++)
        pwr[j] = *(const floatx4*)(projW + j * kH + wv * 16 + l4 * 4);
    float pbr = 0.0f;
    if (tid < 64) pbr = projb[tid & 1];

    auto load_wb = [&](int mat) {
        #pragma unroll
        for (int gt = 0; gt < 4; gt++) {
            #pragma unroll
            for (int kc = 0; kc < 5; kc++) {
                size_t off = ((((size_t)mat * 32 + (gt * 8 + wv)) * 5 + kc) * 64 + lane) * 8;
                wfr[gt][kc] = *(const half8*)(wf + off);
            }
            bs4[gt] = *(const floatx4*)(biases + mat * kG + gt * kH + wv * 16 + l4 * 4);
        }
    };
    load_wb(0);
    __syncthreads();

    float cst[2][4];    // cell state: [btile][jj]
    float hreg[2][4];   // f32 h_new (for exact projection)
    #pragma unroll
    for (int bt = 0; bt < 2; bt++)
        #pragma unroll
        for (int jj = 0; jj < 4; jj++) cst[bt][jj] = 0.0f;

    const int swz = (lane & 7) << 4;      // r&7 == lane&7 for both btiles
    int hoffs[2][4], woff[2];
    #pragma unroll
    for (int bt = 0; bt < 2; bt++) {
        int r = bt * 16 + l15;
        #pragma unroll
        for (int kc = 0; kc < 4; kc++)
            hoffs[bt][kc] = (r * 256 + kc * 64 + l4 * 16) ^ swz;   // ds_read_b128
        woff[bt] = (r * 256 + wv * 32 + l4 * 8) ^ swz;             // ds_write_b64
    }

    auto run_step = [&](const half8 (&xf)[2][2], int curBuf) {
        floatx4 acc[4][2];   // [gate-type][btile]
        #pragma unroll
        for (int gt = 0; gt < 4; gt++) { acc[gt][0] = bs4[gt]; acc[gt][1] = bs4[gt]; }

        const char* baseH = (const char*)&hH[curBuf][0][0];
        const char* baseL = (const char*)&hL[curBuf][0][0];
        // pass 1: W * h_hi
        #pragma unroll
        for (int kc = 0; kc < 4; kc++) {
            half8 b0 = *(const half8*)(baseH + hoffs[0][kc]);
            half8 b1 = *(const half8*)(baseH + hoffs[1][kc]);
            #pragma unroll
            for (int gt = 0; gt < 4; gt++) {
                acc[gt][0] = __builtin_amdgcn_mfma_f32_16x16x32_f16(wfr[gt][kc], b0, acc[gt][0], 0, 0, 0);
                acc[gt][1] = __builtin_amdgcn_mfma_f32_16x16x32_f16(wfr[gt][kc], b1, acc[gt][1], 0, 0, 0);
            }
        }
        #pragma unroll
        for (int gt = 0; gt < 4; gt++) {   // x hi chunk
            acc[gt][0] = __builtin_amdgcn_mfma_f32_16x16x32_f16(wfr[gt][4], xf[0][0], acc[gt][0], 0, 0, 0);
            acc[gt][1] = __builtin_amdgcn_mfma_f32_16x16x32_f16(wfr[gt][4], xf[1][0], acc[gt][1], 0, 0, 0);
        }
        // pass 2: W * h_lo
        #pragma unroll
        for (int kc = 0; kc < 4; kc++) {
            half8 b0 = *(const half8*)(baseL + hoffs[0][kc]);
            half8 b1 = *(const half8*)(baseL + hoffs[1][kc]);
            #pragma unroll
            for (int gt = 0; gt < 4; gt++) {
                acc[gt][0] = __builtin_amdgcn_mfma_f32_16x16x32_f16(wfr[gt][kc], b0, acc[gt][0], 0, 0, 0);
                acc[gt][1] = __builtin_amdgcn_mfma_f32_16x16x32_f16(wfr[gt][kc], b1, acc[gt][1], 0, 0, 0);
            }
        }
        #pragma unroll
        for (int gt = 0; gt < 4; gt++) {   // x lo chunk
            acc[gt][0] = __builtin_amdgcn_mfma_f32_16x16x32_f16(wfr[gt][4], xf[0][1], acc[gt][0], 0, 0, 0);
            acc[gt][1] = __builtin_amdgcn_mfma_f32_16x16x32_f16(wfr[gt][4], xf[1][1], acc[gt][1], 0, 0, 0);
        }

        // cell update — i,f,g,o for the same (row,col) all live in this lane
        char* nH = (char*)&hH[curBuf ^ 1][0][0];
        char* nL = (char*)&hL[curBuf ^ 1][0][0];
        #pragma unroll
        for (int bt = 0; bt < 2; bt++) {
            half4 pH, pL;
            #pragma unroll
            for (int jj = 0; jj < 4; jj++) {
                float iv = sigf(acc[0][bt][jj]);
                float fv = sigf(acc[1][bt][jj]);
                float gv = tanhf_fast(acc[2][bt][jj]);
                float ov = sigf(acc[3][bt][jj]);
                float cn = fv * cst[bt][jj] + iv * gv;
                cst[bt][jj] = cn;
                float hn = ov * tanhf_fast(cn);
                hreg[bt][jj] = hn;
                _Float16 hh = (_Float16)hn;
                pH[jj] = hh;
                pL[jj] = (_Float16)(hn - (float)hh);
            }
            *(half4*)(nH + woff[bt]) = pH;
            *(half4*)(nL + woff[bt]) = pL;
        }
    };

    int cur = 0;

    // ---- encoder ----
    for (int t = 0; t < kTEnc; t++) {
        half8 xf[2][2];
        #pragma unroll
        for (int bt = 0; bt < 2; bt++) {
            xf[bt][0] = *(const half8*)&xsH[t][bt * 16 + l15][0];
            xf[bt][1] = *(const half8*)&xsL[t][bt * 16 + l15][0];
        }
        run_step(xf, cur);
        __syncthreads();
        cur ^= 1;
    }

    // ---- transition: decoder weights + initial input = x[:, -1, :2] ----
    load_wb(1);
    if (tid < 64) {
        int r = tid >> 1, j = tid & 1;
        inp_s[r][j] = (float)xsH[kTEnc - 1][r][j] + (float)xsL[kTEnc - 1][r][j];
    }
    __syncthreads();

    // ---- decoder ----
    for (int t = 0; t < kTDec; t++) {
        half8 xf[2][2];
        #pragma unroll
        for (int bt = 0; bt < 2; bt++) {
            float a0 = inp_s[bt * 16 + l15][0];
            float a1 = inp_s[bt * 16 + l15][1];
            _Float16 h0 = (_Float16)a0, h1 = (_Float16)a1;
            half8 vH, vL;
            #pragma unroll
            for (int e = 0; e < 8; e++) { vH[e] = (_Float16)0.0f; vL[e] = (_Float16)0.0f; }
            vH[0] = h0; vH[1] = h1;
            vL[0] = (_Float16)(a0 - (float)h0);
            vL[1] = (_Float16)(a1 - (float)h1);
            xf[bt][0] = vH; xf[bt][1] = vL;   // lanes>=16 / elems>=2 killed by zero W' pads
        }
        run_step(xf, cur);

        // projection from exact f32 h in registers: partial over this lane's 4 cols
        float pp[2][2];
        #pragma unroll
        for (int bt = 0; bt < 2; bt++)
            #pragma unroll
            for (int j = 0; j < 2; j++)
                pp[bt][j] = hreg[bt][0] * pwr[j][0] + hreg[bt][1] * pwr[j][1]
                          + hreg[bt][2] * pwr[j][2] + hreg[bt][3] * pwr[j][3];
        #pragma unroll
        for (int bt = 0; bt < 2; bt++)
            #pragma unroll
            for (int j = 0; j < 2; j++) {
                float v = pp[bt][j];
                v += __shfl_xor(v, 16);
                v += __shfl_xor(v, 32);
                pp[bt][j] = v;
            }
        if (l4 == 0) {
            #pragma unroll
            for (int bt = 0; bt < 2; bt++) {
                partial[bt * 16 + l15][0][wv] = pp[bt][0];
                partial[bt * 16 + l15][1][wv] = pp[bt][1];
            }
        }
        __syncthreads();
        if (tid < 64) {
            int r = tid >> 1, j = tid & 1;
            float s = pbr;
            #pragma unroll
            for (int ww = 0; ww < 8; ww++) s += partial[r][j][ww];
            out[(size_t)(rowBase + r) * (kTDec * 2) + t * 2 + j] = s;
            inp_s[r][j] = s;
        }
        __syncthreads();
        cur ^= 1;
    }
}

extern "C" void kernel_launch(void* const* d_in, const int* in_sizes, int n_in,
                              void* d_out, int out_size, void* d_ws, size_t ws_size,
                              hipStream_t stream) {
    const float* x      = (const float*)d_in[0];
    const float* encWih = (const float*)d_in[1];
    const float* encWhh = (const float*)d_in[2];
    const float* encbih = (const float*)d_in[3];
    const float* encbhh = (const float*)d_in[4];
    const float* decWih = (const float*)d_in[5];
    const float* decWhh = (const float*)d_in[6];
    const float* decbih = (const float*)d_in[7];
    const float* decbhh = (const float*)d_in[8];
    const float* projW  = (const float*)d_in[9];
    const float* projb  = (const float*)d_in[10];

    _Float16* wfrag = (_Float16*)d_ws;
    float* biases = (float*)((char*)d_ws + (size_t)kWfHalves * 2);
    float* out = (float*)d_out;

    lstm_prep<<<80, 256, 0, stream>>>(encWhh, encWih, decWhh, decWih,
                                      encbih, encbhh, decbih, decbhh,
                                      wfrag, biases);
    lstm_main<<<256, kThreads, 0, stream>>>(x, wfrag, biases, projW, projb, out);
}

// Round 3
// 391.855 us; speedup vs baseline: 5.4246x; 1.0734x over previous
//
#include <hip/hip_runtime.h>
#include <cstddef>

typedef __attribute__((ext_vector_type(8))) _Float16 half8;
typedef __attribute__((ext_vector_type(4))) _Float16 half4;
typedef __attribute__((ext_vector_type(4))) float floatx4;

namespace {
constexpr int kH = 128;
constexpr int kG = 512;          // 4*H
constexpr int kTEnc = 50;
constexpr int kTDec = 60;
constexpr int kRows = 16;        // batch rows per block
constexpr int kThreads = 512;    // 8 waves
constexpr int kWfHalves = 2 * 32 * 5 * 64 * 8;   // W' frags: [mat][gtile][kc][lane][j]
}

// Pack W' = [Whh | Wih | pad] (512 x 160) as fp16 MFMA A-fragments, plus fused biases.
// Fragment element (mat, gtile, kc, lane, j) holds W'[gtile*16 + (lane&15)][kc*32 + (lane>>4)*8 + j].
// Main kernel uses the SAME (lane,j)->k map for B (h/x) fragments -> contraction is
// correct independent of HW k-ordering (dot products are permutation-invariant).
__global__ void lstm_prep(const float* __restrict__ encWhh, const float* __restrict__ encWih,
                          const float* __restrict__ decWhh, const float* __restrict__ decWih,
                          const float* __restrict__ encbih, const float* __restrict__ encbhh,
                          const float* __restrict__ decbih, const float* __restrict__ decbhh,
                          _Float16* __restrict__ wf, float* __restrict__ bias_out) {
    int idx = blockIdx.x * 256 + threadIdx.x;
    if (idx < 2 * 32 * 5 * 64) {
        const int lane = idx & 63;
        const int kc   = (idx >> 6) % 5;
        const int gt   = (idx / 320) & 31;
        const int mat  = idx / 10240;
        const float* Whh = mat ? decWhh : encWhh;
        const float* Wih = mat ? decWih : encWih;
        const int din = mat ? 2 : 6;
        const int g = gt * 16 + (lane & 15);
        _Float16 vals[8];
        #pragma unroll
        for (int j = 0; j < 8; j++) {
            int k = kc * 32 + (lane >> 4) * 8 + j;
            float v = 0.0f;
            if (k < kH) v = Whh[g * kH + k];
            else if (k - kH < din) v = Wih[g * din + (k - kH)];
            vals[j] = (_Float16)v;
        }
        *(half8*)(wf + (size_t)idx * 8) = *(half8*)vals;
    }
    if (idx < 2 * kG) {
        int mat = idx >> 9, g = idx & (kG - 1);
        bias_out[idx] = mat ? (decbih[g] + decbhh[g]) : (encbih[g] + encbhh[g]);
    }
}

__global__ __launch_bounds__(kThreads, 4) void lstm_main(
    const float* __restrict__ x,
    const _Float16* __restrict__ wf,
    const float* __restrict__ biases,
    const float* __restrict__ projW,
    const float* __restrict__ projb,
    float* __restrict__ out)
{
    __shared__ alignas(16) _Float16 xsH[kTEnc][kRows][8];   // x hi, zero-padded d=6,7
    __shared__ alignas(16) _Float16 xsL[kTEnc][kRows][8];   // x lo
    __shared__ alignas(16) _Float16 hH[2][kRows][kH];       // h (f16, XOR-swizzled), ping-pong
    __shared__ float inp_s[kRows][2];
    __shared__ float partial[kRows][2][8];

    const int tid  = threadIdx.x;
    const int lane = tid & 63;
    const int wv   = tid >> 6;        // wave 0..7: owns gate-cols [16wv,16wv+16) of each gate
    const int l15  = lane & 15;
    const int l4   = lane >> 4;
    const int rowBase = blockIdx.x * kRows;

    // ---- stage x (split to f16 hi/lo, t-major for conflict-free fragment reads) ----
    for (int i = tid; i < kTEnc * kRows * 8; i += kThreads) {
        int d = i & 7;
        int r = (i >> 3) & (kRows - 1);
        int t = i >> 7;
        float v = (d < 6) ? x[(size_t)(rowBase + r) * (kTEnc * 6) + t * 6 + d] : 0.0f;
        _Float16 hi = (_Float16)v;
        xsH[t][r][d] = hi;
        xsL[t][r][d] = (_Float16)(v - (float)hi);
    }
    for (int i = tid; i < kRows * kH; i += kThreads)
        (&hH[0][0][0])[i] = (_Float16)0.0f;

    // ---- per-wave register-resident weights / biases / proj slice ----
    half8  wfr[4][5];   // [gate-type][kchunk], 80 VGPR
    floatx4 bs4[4];
    floatx4 pwr[2];     // projW[j] at this lane's 4 cols
    #pragma unroll
    for (int j = 0; j < 2; j++)
        pwr[j] = *(const floatx4*)(projW + j * kH + wv * 16 + l4 * 4);
    float pbr = 0.0f;
    if (tid < 2 * kRows) pbr = projb[tid & 1];

    auto load_wb = [&](int mat) {
        #pragma unroll
        for (int gt = 0; gt < 4; gt++) {
            #pragma unroll
            for (int kc = 0; kc < 5; kc++) {
                size_t off = ((((size_t)mat * 32 + (gt * 8 + wv)) * 5 + kc) * 64 + lane) * 8;
                wfr[gt][kc] = *(const half8*)(wf + off);
            }
            bs4[gt] = *(const floatx4*)(biases + mat * kG + gt * kH + wv * 16 + l4 * 4);
        }
    };
    load_wb(0);
    __syncthreads();

    float cst[4];       // cell state per owned col
    float hreg[4];      // f32 h_new (for exact projection)
    #pragma unroll
    for (int jj = 0; jj < 4; jj++) cst[jj] = 0.0f;

    const int swz = (l15 & 7) << 4;
    int hoffs[4], woff;
    #pragma unroll
    for (int kc = 0; kc < 4; kc++)
        hoffs[kc] = (l15 * 256 + kc * 64 + l4 * 16) ^ swz;   // ds_read_b128
    woff = (l15 * 256 + wv * 32 + l4 * 8) ^ swz;             // ds_write_b64

    auto run_step = [&](const half8 (&xf)[2], int curBuf) {
        floatx4 acc[4];
        #pragma unroll
        for (int gt = 0; gt < 4; gt++) acc[gt] = bs4[gt];

        const char* baseH = (const char*)&hH[curBuf][0][0];
        #pragma unroll
        for (int kc = 0; kc < 4; kc++) {
            half8 b0 = *(const half8*)(baseH + hoffs[kc]);
            #pragma unroll
            for (int gt = 0; gt < 4; gt++)
                acc[gt] = __builtin_amdgcn_mfma_f32_16x16x32_f16(wfr[gt][kc], b0, acc[gt], 0, 0, 0);
        }
        #pragma unroll
        for (int gt = 0; gt < 4; gt++) {   // x hi then x lo through the same W' chunk
            acc[gt] = __builtin_amdgcn_mfma_f32_16x16x32_f16(wfr[gt][4], xf[0], acc[gt], 0, 0, 0);
            acc[gt] = __builtin_amdgcn_mfma_f32_16x16x32_f16(wfr[gt][4], xf[1], acc[gt], 0, 0, 0);
        }

        // cell update — i,f,g,o for the same (row,col) live in this lane.
        // batched-rcp forms: sig(i)*tanh(g) = e^i (e^2g - 1) / ((1+e^i)(1+e^2g))
        char* nH = (char*)&hH[curBuf ^ 1][0][0];
        half4 pH;
        #pragma unroll
        for (int jj = 0; jj < 4; jj++) {
            float e_i = __expf(acc[0][jj]);
            float f_v = 1.0f / (1.0f + __expf(-acc[1][jj]));
            float e_g = __expf(2.0f * acc[2][jj]);
            float r1  = 1.0f / ((1.0f + e_i) * (1.0f + e_g));
            float cn  = f_v * cst[jj] + (e_i * (e_g - 1.0f)) * r1;
            cst[jj] = cn;
            float e_o = __expf(acc[3][jj]);
            float e_c = __expf(2.0f * cn);
            float r2  = 1.0f / ((1.0f + e_o) * (1.0f + e_c));
            float hn  = (e_o * (e_c - 1.0f)) * r2;
            hreg[jj] = hn;
            pH[jj] = (_Float16)hn;
        }
        *(half4*)(nH + woff) = pH;
    };

    int cur = 0;

    // ---- encoder ----
    for (int t = 0; t < kTEnc; t++) {
        half8 xf[2];
        xf[0] = *(const half8*)&xsH[t][l15][0];
        xf[1] = *(const half8*)&xsL[t][l15][0];
        run_step(xf, cur);
        __syncthreads();
        cur ^= 1;
    }

    // ---- transition: decoder weights + initial input = x[:, -1, :2] ----
    load_wb(1);
    if (tid < 2 * kRows) {
        int r = tid >> 1, j = tid & 1;
        inp_s[r][j] = (float)xsH[kTEnc - 1][r][j] + (float)xsL[kTEnc - 1][r][j];
    }
    __syncthreads();

    // ---- decoder ----
    for (int t = 0; t < kTDec; t++) {
        half8 xf[2];
        {
            float a0 = inp_s[l15][0];
            float a1 = inp_s[l15][1];
            _Float16 h0 = (_Float16)a0, h1 = (_Float16)a1;
            half8 vH, vL;
            #pragma unroll
            for (int e = 0; e < 8; e++) { vH[e] = (_Float16)0.0f; vL[e] = (_Float16)0.0f; }
            vH[0] = h0; vH[1] = h1;
            vL[0] = (_Float16)(a0 - (float)h0);
            vL[1] = (_Float16)(a1 - (float)h1);
            xf[0] = vH; xf[1] = vL;   // lanes l4>0 / elems>=2 killed by zero W' pads
        }
        run_step(xf, cur);

        // projection from exact f32 h in registers: partial over this lane's 4 cols
        float pp[2];
        #pragma unroll
        for (int j = 0; j < 2; j++) {
            float v = hreg[0] * pwr[j][0] + hreg[1] * pwr[j][1]
                    + hreg[2] * pwr[j][2] + hreg[3] * pwr[j][3];
            v += __shfl_xor(v, 16);
            v += __shfl_xor(v, 32);
            pp[j] = v;
        }
        if (l4 == 0) {
            partial[l15][0][wv] = pp[0];
            partial[l15][1][wv] = pp[1];
        }
        __syncthreads();
        if (tid < 2 * kRows) {
            int r = tid >> 1, j = tid & 1;
            float s = pbr;
            #pragma unroll
            for (int ww = 0; ww < 8; ww++) s += partial[r][j][ww];
            out[(size_t)(rowBase + r) * (kTDec * 2) + t * 2 + j] = s;
            inp_s[r][j] = s;
        }
        __syncthreads();
        cur ^= 1;
    }
}

extern "C" void kernel_launch(void* const* d_in, const int* in_sizes, int n_in,
                              void* d_out, int out_size, void* d_ws, size_t ws_size,
                              hipStream_t stream) {
    const float* x      = (const float*)d_in[0];
    const float* encWih = (const float*)d_in[1];
    const float* encWhh = (const float*)d_in[2];
    const float* encbih = (const float*)d_in[3];
    const float* encbhh = (const float*)d_in[4];
    const float* decWih = (const float*)d_in[5];
    const float* decWhh = (const float*)d_in[6];
    const float* decbih = (const float*)d_in[7];
    const float* decbhh = (const float*)d_in[8];
    const float* projW  = (const float*)d_in[9];
    const float* projb  = (const float*)d_in[10];

    _Float16* wfrag = (_Float16*)d_ws;
    float* biases = (float*)((char*)d_ws + (size_t)kWfHalves * 2);
    float* out = (float*)d_out;

    lstm_prep<<<80, 256, 0, stream>>>(encWhh, encWih, decWhh, decWih,
                                      encbih, encbhh, decbih, decbhh,
                                      wfrag, biases);
    // 512 blocks x 512 threads (8 waves), 16 rows each -> 2 blocks/CU, 16 waves/CU
    lstm_main<<<kRows * 8192 / kRows / kRows, kThreads, 0, stream>>>(
        x, wfrag, biases, projW, projb, out);
}

// Round 4
// 271.308 us; speedup vs baseline: 7.8348x; 1.4443x over previous
//
#include <hip/hip_runtime.h>
#include <cstddef>

typedef __attribute__((ext_vector_type(8))) _Float16 half8;
typedef __attribute__((ext_vector_type(4))) _Float16 half4;
typedef __attribute__((ext_vector_type(4))) float floatx4;

namespace {
constexpr int kH = 128;
constexpr int kTEnc = 50;
constexpr int kTDec = 60;
constexpr int kRows = 16;        // batch rows per block
constexpr int kThreads = 512;    // 8 waves
constexpr int kBTot = 8192;
}

// W' = [Whh (k=0..127) | Wih hi-copy (k=128..128+din) | Wih lo-copy (k=136..136+din)
//       | bias hi (k=144) | bias lo (k=145) | 0 ] packed as fp16 MFMA A-fragments.
// Fragment element (mat, gtile, kc, lane, j) holds W'[gtile*16 + (lane&15)][kc*32 + (lane>>4)*8 + j].
// The main kernel uses the SAME (lane,j)->k map for its B fragments, so the contraction
// is correct independent of HW k-ordering (dot products are permutation-invariant).
__global__ void lstm_prep(const float* __restrict__ encWhh, const float* __restrict__ encWih,
                          const float* __restrict__ decWhh, const float* __restrict__ decWih,
                          const float* __restrict__ encbih, const float* __restrict__ encbhh,
                          const float* __restrict__ decbih, const float* __restrict__ decbhh,
                          _Float16* __restrict__ wf) {
    int idx = blockIdx.x * 256 + threadIdx.x;   // [mat][gtile][kc][lane]: 2*32*5*64
    if (idx >= 2 * 32 * 5 * 64) return;
    const int lane = idx & 63;
    const int kc   = (idx >> 6) % 5;
    const int gt   = (idx / 320) & 31;
    const int mat  = idx / 10240;
    const float* Whh = mat ? decWhh : encWhh;
    const float* Wih = mat ? decWih : encWih;
    const float* bih = mat ? decbih : encbih;
    const float* bhh = mat ? decbhh : encbhh;
    const int din = mat ? 2 : 6;
    const int g = gt * 16 + (lane & 15);
    _Float16 vals[8];
    #pragma unroll
    for (int j = 0; j < 8; j++) {
        int k = kc * 32 + (lane >> 4) * 8 + j;
        float v = 0.0f;
        if (k < kH) {
            v = Whh[g * kH + k];
        } else {
            int kk = k - kH;                    // 0..31
            if (kk < din)                       v = Wih[g * din + kk];        // * x_hi
            else if (kk >= 8 && kk < 8 + din)   v = Wih[g * din + (kk - 8)];  // * x_lo
            else if (kk == 16)                  v = bih[g] + bhh[g];          // * 1 (hi)
            else if (kk == 17) { float b = bih[g] + bhh[g]; v = b - (float)(_Float16)b; } // * 1 (lo)
        }
        vals[j] = (_Float16)v;
    }
    *(half8*)(wf + (size_t)idx * 8) = *(half8*)vals;
}

__global__ __launch_bounds__(kThreads, 2) void lstm_main(
    const float* __restrict__ x,
    const _Float16* __restrict__ wf,
    const float* __restrict__ projW,
    const float* __restrict__ projb,
    float* __restrict__ out)
{
    __shared__ alignas(16) _Float16 xs[kTEnc][kRows][2][8];  // [t][r][hi/lo][d], 25.6 KB
    __shared__ alignas(16) _Float16 hbuf[2][kRows][kH];      // h f16, XOR-swizzled, ping-pong
    __shared__ alignas(16) _Float16 decf[kRows][2][8];       // decoder feedback hi/lo frags
    __shared__ alignas(16) _Float16 ones16[8];               // {1,1,0,...} bias-activator frag
    __shared__ alignas(16) _Float16 zeros16[8];
    __shared__ float pw_s[2][kH];
    __shared__ float partial[kRows][2][8];

    const int tid  = threadIdx.x;
    const int lane = tid & 63;
    const int wv   = tid >> 6;        // wave 0..7: owns gate-cols [16wv,16wv+16) of each gate
    const int l15  = lane & 15;
    const int l4   = lane >> 4;
    const int rowBase = blockIdx.x * kRows;

    // ---- one-time staging ----
    for (int i = tid; i < kTEnc * kRows * 8; i += kThreads) {
        int d = i & 7;
        int r = (i >> 3) & (kRows - 1);
        int t = i >> 7;
        float v = (d < 6) ? x[(size_t)(rowBase + r) * (kTEnc * 6) + t * 6 + d] : 0.0f;
        _Float16 hi = (_Float16)v;
        xs[t][r][0][d] = hi;
        xs[t][r][1][d] = (_Float16)(v - (float)hi);
    }
    for (int i = tid; i < kRows * kH; i += kThreads)
        (&hbuf[0][0][0])[i] = (_Float16)0.0f;
    for (int i = tid; i < kRows * 16; i += kThreads)
        (&decf[0][0][0])[i] = (_Float16)0.0f;
    for (int i = tid; i < 2 * kH; i += kThreads)
        pw_s[i >> 7][i & (kH - 1)] = projW[i];
    if (tid < 8) {
        ones16[tid] = (_Float16)(tid < 2 ? 1.0f : 0.0f);
        zeros16[tid] = (_Float16)0.0f;
    }

    // ---- per-wave register-resident weights ----
    half8 wfr[4][5];   // [gate-type][kchunk], 80 VGPR
    auto load_w = [&](int mat) {
        #pragma unroll
        for (int gt = 0; gt < 4; gt++)
            #pragma unroll
            for (int kc = 0; kc < 5; kc++) {
                size_t off = ((((size_t)mat * 32 + (gt * 8 + wv)) * 5 + kc) * 64 + lane) * 8;
                wfr[gt][kc] = *(const half8*)(wf + off);
            }
    };
    load_w(0);

    float pbr = 0.0f;
    if (tid < 2 * kRows) pbr = projb[tid & 1];
    __syncthreads();

    float cst[4];      // cell state per owned col
    float hreg[4];     // f32 h_new (for exact projection)
    #pragma unroll
    for (int jj = 0; jj < 4; jj++) cst[jj] = 0.0f;

    const int swz = (l15 & 7) << 4;
    int hoffs[4], woff;
    #pragma unroll
    for (int kc = 0; kc < 4; kc++)
        hoffs[kc] = (l15 * 256 + kc * 64 + l4 * 16) ^ swz;   // ds_read_b128
    woff = (l15 * 256 + wv * 32 + l4 * 8) ^ swz;             // ds_write_b64

    // x-chunk B-fragment addresses (lane-selected): l4=0 -> hi, l4=1 -> lo,
    // l4=2 -> {1,1,0..} (activates bias cols), l4=3 -> zeros.
    const char* xconst = (l4 == 2) ? (const char*)ones16 : (const char*)zeros16;
    const char* encXbase = (l4 < 2) ? ((const char*)xs + l15 * 32 + l4 * 16) : xconst;
    const int   encXstep = (l4 < 2) ? (kRows * 2 * 8 * 2) : 0;   // 512 B per t
    const char* decXaddr = (l4 < 2) ? ((const char*)decf + l15 * 32 + l4 * 16) : xconst;

    auto run_step = [&](half8 bx, int curBuf) {
        const floatx4 z = {0.0f, 0.0f, 0.0f, 0.0f};
        floatx4 acc[4] = {z, z, z, z};
        const char* baseH = (const char*)&hbuf[curBuf][0][0];
        #pragma unroll
        for (int kc = 0; kc < 4; kc++) {
            half8 b0 = *(const half8*)(baseH + hoffs[kc]);
            #pragma unroll
            for (int gt = 0; gt < 4; gt++)
                acc[gt] = __builtin_amdgcn_mfma_f32_16x16x32_f16(wfr[gt][kc], b0, acc[gt], 0, 0, 0);
        }
        #pragma unroll
        for (int gt = 0; gt < 4; gt++)
            acc[gt] = __builtin_amdgcn_mfma_f32_16x16x32_f16(wfr[gt][4], bx, acc[gt], 0, 0, 0);

        // cell update — i,f,g,o of the same (row,col) live in this lane.
        // shared-rcp forms: sig(f)*c + sig(i)*tanh(g)
        //   = r * [ (1+e_i)(1+e_g)*c + e_i(e_g-1)(1+e_mf) ],  r = 1/((1+e_mf)(1+e_i)(1+e_g))
        char* nH = (char*)&hbuf[curBuf ^ 1][0][0];
        half4 pH;
        #pragma unroll
        for (int jj = 0; jj < 4; jj++) {
            float e_i  = __expf(acc[0][jj]);
            float e_mf = __expf(-acc[1][jj]);
            float e_g  = __expf(2.0f * acc[2][jj]);
            float a    = (1.0f + e_i) * (1.0f + e_g);
            float r1   = 1.0f / (a * (1.0f + e_mf));
            float cn   = r1 * (a * cst[jj] + e_i * (e_g - 1.0f) * (1.0f + e_mf));
            cst[jj] = cn;
            float e_o  = __expf(acc[3][jj]);
            float e_c  = __expf(2.0f * cn);
            float r2   = 1.0f / ((1.0f + e_o) * (1.0f + e_c));
            float hn   = (e_o * (e_c - 1.0f)) * r2;
            hreg[jj] = hn;
            pH[jj] = (_Float16)hn;
        }
        *(half4*)(nH + woff) = pH;
    };

    int cur = 0;

    // ---- encoder: 50 steps, one barrier each ----
    for (int t = 0; t < kTEnc; t++) {
        half8 bx = *(const half8*)(encXbase + t * encXstep);
        run_step(bx, cur);
        __syncthreads();
        cur ^= 1;
    }

    // ---- transition: decoder weights + initial input = x[:, -1, :2] ----
    load_w(1);
    if (tid < 2 * kRows) {
        int r = tid >> 1, j = tid & 1;
        decf[r][0][j] = xs[kTEnc - 1][r][0][j];
        decf[r][1][j] = xs[kTEnc - 1][r][1][j];
    }
    __syncthreads();

    // ---- decoder: 60 steps ----
    for (int t = 0; t < kTDec; t++) {
        half8 bx = *(const half8*)decXaddr;
        run_step(bx, cur);

        // projection from exact f32 h in registers over this lane's 4 cols
        floatx4 pw0 = *(const floatx4*)&pw_s[0][wv * 16 + l4 * 4];
        floatx4 pw1 = *(const floatx4*)&pw_s[1][wv * 16 + l4 * 4];
        float pp[2];
        #pragma unroll
        for (int j = 0; j < 2; j++) {
            const floatx4& pw = j ? pw1 : pw0;
            float v = hreg[0] * pw[0] + hreg[1] * pw[1] + hreg[2] * pw[2] + hreg[3] * pw[3];
            v += __shfl_xor(v, 16);
            v += __shfl_xor(v, 32);
            pp[j] = v;
        }
        if (l4 == 0) {
            partial[l15][0][wv] = pp[0];
            partial[l15][1][wv] = pp[1];
        }
        __syncthreads();
        if (tid < 2 * kRows) {
            int r = tid >> 1, j = tid & 1;
            float s = pbr;
            #pragma unroll
            for (int ww = 0; ww < 8; ww++) s += partial[r][j][ww];
            out[(size_t)(rowBase + r) * (kTDec * 2) + t * 2 + j] = s;
            _Float16 hi = (_Float16)s;
            decf[r][0][j] = hi;
            decf[r][1][j] = (_Float16)(s - (float)hi);
        }
        __syncthreads();
        cur ^= 1;
    }
}

extern "C" void kernel_launch(void* const* d_in, const int* in_sizes, int n_in,
                              void* d_out, int out_size, void* d_ws, size_t ws_size,
                              hipStream_t stream) {
    const float* x      = (const float*)d_in[0];
    const float* encWih = (const float*)d_in[1];
    const float* encWhh = (const float*)d_in[2];
    const float* encbih = (const float*)d_in[3];
    const float* encbhh = (const float*)d_in[4];
    const float* decWih = (const float*)d_in[5];
    const float* decWhh = (const float*)d_in[6];
    const float* decbih = (const float*)d_in[7];
    const float* decbhh = (const float*)d_in[8];
    const float* projW  = (const float*)d_in[9];
    const float* projb  = (const float*)d_in[10];

    _Float16* wfrag = (_Float16*)d_ws;
    float* out = (float*)d_out;

    lstm_prep<<<80, 256, 0, stream>>>(encWhh, encWih, decWhh, decWih,
                                      encbih, encbhh, decbih, decbhh, wfrag);
    // 512 blocks x 512 threads (8 waves), 16 rows each -> 2 blocks/CU, 16 waves/CU
    lstm_main<<<kBTot / kRows, kThreads, 0, stream>>>(x, wfrag, projW, projb, out);
}

// Round 5
// 197.310 us; speedup vs baseline: 10.7731x; 1.3750x over previous
//
#include <hip/hip_runtime.h>
#include <cstddef>

typedef __attribute__((ext_vector_type(8))) _Float16 half8;
typedef __attribute__((ext_vector_type(4))) _Float16 half4;
typedef __attribute__((ext_vector_type(4))) float floatx4;

namespace {
constexpr int kH = 128;
constexpr int kTEnc = 50;
constexpr int kTDec = 60;
constexpr int kRows = 16;        // batch rows per block
constexpr int kThreads = 512;    // 8 waves
constexpr int kBTot = 8192;
}

__device__ __forceinline__ float fexp2(float x) {   // v_exp_f32: 2^x
#if __has_builtin(__builtin_amdgcn_exp2f)
    return __builtin_amdgcn_exp2f(x);
#else
    float r; asm("v_exp_f32 %0, %1" : "=v"(r) : "v"(x)); return r;
#endif
}
__device__ __forceinline__ float frcp(float x) {    // v_rcp_f32 (~1 ulp)
#if __has_builtin(__builtin_amdgcn_rcpf)
    return __builtin_amdgcn_rcpf(x);
#else
    float r; asm("v_rcp_f32 %0, %1" : "=v"(r) : "v"(x)); return r;
#endif
}

// W' packed as fp16 MFMA A-fragments, 3 weight sets:
//   mat 0: encoder  [Whh | Wih hi | Wih lo | bias]     (din=6)
//   mat 1: decoder step-1 (unfused)                     (din=2)
//   mat 2: decoder steps 2..60: W~ = decWhh + decWih@projW, b~ = b + decWih@projb (din=0)
// All rows pre-scaled: i,o: +log2e; f: -log2e (so exp2(acc) = e^{-f}); g: +2*log2e.
// Bias lives in k-cols 144(hi)/145(lo), activated by a {1,1,0..} B-fragment at l4==2.
// Fragment element (mat,gtile,kc,lane,j) = W'[gtile*16+(lane&15)][kc*32+(lane>>4)*8+j];
// the main kernel uses the SAME (lane,j)->k map for B fragments (permutation-invariant dot).
__global__ void lstm_prep(const float* __restrict__ encWhh, const float* __restrict__ encWih,
                          const float* __restrict__ decWhh, const float* __restrict__ decWih,
                          const float* __restrict__ encbih, const float* __restrict__ encbhh,
                          const float* __restrict__ decbih, const float* __restrict__ decbhh,
                          const float* __restrict__ projW,  const float* __restrict__ projb,
                          _Float16* __restrict__ wf) {
    int idx = blockIdx.x * 256 + threadIdx.x;   // [mat][gtile][kc][lane]: 3*32*5*64
    if (idx >= 3 * 32 * 5 * 64) return;
    const int lane = idx & 63;
    const int kc   = (idx >> 6) % 5;
    const int gt   = (idx / 320) & 31;
    const int mat  = idx / 10240;
    const float* Whh = (mat == 0) ? encWhh : decWhh;
    const float* Wih = (mat == 0) ? encWih : decWih;
    const float* bih = (mat == 0) ? encbih : decbih;
    const float* bhh = (mat == 0) ? encbhh : decbhh;
    const int din = (mat == 0) ? 6 : (mat == 1) ? 2 : 0;
    const int g = gt * 16 + (lane & 15);
    const int gtype = g >> 7;                   // 0:i 1:f 2:g 3:o
    const float L2E = 1.4426950408889634f;
    const float sc = (gtype == 1) ? -L2E : (gtype == 2) ? 2.0f * L2E : L2E;

    float b = bih[g] + bhh[g];
    if (mat == 2) b += decWih[g * 2 + 0] * projb[0] + decWih[g * 2 + 1] * projb[1];
    const float bs = sc * b;

    _Float16 vals[8];
    #pragma unroll
    for (int j = 0; j < 8; j++) {
        int k = kc * 32 + (lane >> 4) * 8 + j;
        float v = 0.0f;
        if (k < kH) {
            v = Whh[g * kH + k];
            if (mat == 2)
                v += decWih[g * 2 + 0] * projW[k] + decWih[g * 2 + 1] * projW[kH + k];
            v *= sc;
        } else {
            int kk = k - kH;                    // 0..31
            if (kk < din)                       v = sc * Wih[g * din + kk];         // * x_hi
            else if (kk >= 8 && kk < 8 + din)   v = sc * Wih[g * din + (kk - 8)];   // * x_lo
            else if (kk == 16)                  v = bs;                              // hi (f16 cast below)
            else if (kk == 17)                  v = bs - (float)(_Float16)bs;        // lo
        }
        vals[j] = (_Float16)v;
    }
    *(half8*)(wf + (size_t)idx * 8) = *(half8*)vals;
}

__global__ __launch_bounds__(kThreads, 2) void lstm_main(
    const float* __restrict__ x,
    const _Float16* __restrict__ wf,
    const float* __restrict__ projW,
    const float* __restrict__ projb,
    float* __restrict__ out)
{
    __shared__ alignas(16) _Float16 xs[kTEnc][kRows][2][8];  // [t][r][hi/lo][d]
    __shared__ alignas(16) _Float16 hbuf[2][kRows][kH];      // h f16, XOR-swizzled, ping-pong
    __shared__ alignas(16) _Float16 decf[kRows][2][8];       // dec step-1 input hi/lo frags
    __shared__ alignas(16) _Float16 ones16[8];               // {1,1,0,...} bias activator
    __shared__ alignas(16) _Float16 zeros16[8];
    __shared__ alignas(8)  float partial[2][8][16][2];       // [parity][wv][r][j]
    __shared__ float pb_s[2];

    const int tid  = threadIdx.x;
    const int lane = tid & 63;
    const int wv   = tid >> 6;        // wave: owns gate-cols [16wv,16wv+16) of each gate
    const int l15  = lane & 15;
    const int l4   = lane >> 4;
    const int rowBase = blockIdx.x * kRows;

    // ---- one-time staging ----
    for (int i = tid; i < kTEnc * kRows * 8; i += kThreads) {
        int d = i & 7;
        int r = (i >> 3) & (kRows - 1);
        int t = i >> 7;
        float v = (d < 6) ? x[(size_t)(rowBase + r) * (kTEnc * 6) + t * 6 + d] : 0.0f;
        _Float16 hi = (_Float16)v;
        xs[t][r][0][d] = hi;
        xs[t][r][1][d] = (_Float16)(v - (float)hi);
    }
    for (int i = tid; i < kRows * kH; i += kThreads)
        (&hbuf[0][0][0])[i] = (_Float16)0.0f;
    for (int i = tid; i < kRows * 16; i += kThreads)
        (&decf[0][0][0])[i] = (_Float16)0.0f;
    if (tid < 8) {
        ones16[tid] = (_Float16)(tid < 2 ? 1.0f : 0.0f);
        zeros16[tid] = (_Float16)0.0f;
    }
    if (tid < 2) pb_s[tid] = projb[tid];

    // per-lane projW slice (4 cols owned by this lane)
    floatx4 pwr[2];
    #pragma unroll
    for (int j = 0; j < 2; j++)
        pwr[j] = *(const floatx4*)(projW + j * kH + wv * 16 + l4 * 4);

    // ---- per-wave register-resident weights ----
    half8 wfr[4][5];   // [gate-type][kchunk]
    auto load_w = [&](int mat) {
        #pragma unroll
        for (int gt = 0; gt < 4; gt++)
            #pragma unroll
            for (int kc = 0; kc < 5; kc++) {
                size_t off = ((((size_t)mat * 32 + (gt * 8 + wv)) * 5 + kc) * 64 + lane) * 8;
                wfr[gt][kc] = *(const half8*)(wf + off);
            }
    };
    load_w(0);
    __syncthreads();

    float cst[4];      // cell state per owned col
    float hreg[4];     // f32 h_new (for projection)
    #pragma unroll
    for (int jj = 0; jj < 4; jj++) cst[jj] = 0.0f;

    const int swz = (l15 & 7) << 4;
    int hoffs[4], woff;
    #pragma unroll
    for (int kc = 0; kc < 4; kc++)
        hoffs[kc] = (l15 * 256 + kc * 64 + l4 * 16) ^ swz;   // ds_read_b128
    woff = (l15 * 256 + wv * 32 + l4 * 8) ^ swz;             // ds_write_b64

    // 5th-chunk B-frag addresses: l4=0 -> x hi, l4=1 -> x lo, l4=2 -> ones (bias), l4=3 -> zeros
    const char* xconst = (l4 == 2) ? (const char*)ones16 : (const char*)zeros16;
    const char* encXbase = (l4 < 2) ? ((const char*)xs + l15 * 32 + l4 * 16) : xconst;
    const int   encXstep = (l4 < 2) ? (kRows * 2 * 8 * 2) : 0;   // 512 B per t
    const char* decXaddr1 = (l4 < 2) ? ((const char*)decf + l15 * 32 + l4 * 16) : xconst;
    const char* decXaddrN = xconst;   // fused steps: bias only

    constexpr float kK2 = 2.8853900817779268f;   // 2*log2(e)

    auto run_step = [&](half8 bx, int curBuf) {
        const floatx4 z = {0.0f, 0.0f, 0.0f, 0.0f};
        floatx4 acc[4] = {z, z, z, z};
        const char* baseH = (const char*)&hbuf[curBuf][0][0];
        #pragma unroll
        for (int kc = 0; kc < 4; kc++) {
            half8 b0 = *(const half8*)(baseH + hoffs[kc]);
            #pragma unroll
            for (int gt = 0; gt < 4; gt++)
                acc[gt] = __builtin_amdgcn_mfma_f32_16x16x32_f16(wfr[gt][kc], b0, acc[gt], 0, 0, 0);
        }
        #pragma unroll
        for (int gt = 0; gt < 4; gt++)
            acc[gt] = __builtin_amdgcn_mfma_f32_16x16x32_f16(wfr[gt][4], bx, acc[gt], 0, 0, 0);

        // i,f,g,o of the same (row,col) live in this lane; accs are pre-scaled so
        // exp2 gives e^i, e^{-f}, e^{2g}, e^o directly.
        char* nH = (char*)&hbuf[curBuf ^ 1][0][0];
        half4 pH;
        #pragma unroll
        for (int jj = 0; jj < 4; jj++) {
            float e_i  = fexp2(acc[0][jj]);
            float e_mf = fexp2(acc[1][jj]);
            float e_g  = fexp2(acc[2][jj]);
            float A    = (1.0f + e_i) * (1.0f + e_g);
            float r1   = frcp(A * (1.0f + e_mf));
            float cn   = r1 * fmaf(e_i * (e_g - 1.0f), 1.0f + e_mf, A * cst[jj]);
            cst[jj] = cn;
            float e_o  = fexp2(acc[3][jj]);
            float e_c  = fexp2(kK2 * cn);
            float r2   = frcp((1.0f + e_o) * (1.0f + e_c));
            float hn   = e_o * (e_c - 1.0f) * r2;
            hreg[jj] = hn;
            pH[jj] = (_Float16)hn;
        }
        *(half4*)(nH + woff) = pH;
    };

    int cur = 0;

    // ---- encoder: 50 steps, one barrier each ----
    for (int t = 0; t < kTEnc; t++) {
        half8 bx = *(const half8*)(encXbase + t * encXstep);
        run_step(bx, cur);
        __syncthreads();
        cur ^= 1;
    }

    // projection partial from this lane's 4 cols -> per-wave partial in LDS
    auto proj_partial = [&](int par) {
        float pp0 = hreg[0] * pwr[0][0] + hreg[1] * pwr[0][1]
                  + hreg[2] * pwr[0][2] + hreg[3] * pwr[0][3];
        float pp1 = hreg[0] * pwr[1][0] + hreg[1] * pwr[1][1]
                  + hreg[2] * pwr[1][2] + hreg[3] * pwr[1][3];
        pp0 += __shfl_xor(pp0, 16); pp0 += __shfl_xor(pp0, 32);
        pp1 += __shfl_xor(pp1, 16); pp1 += __shfl_xor(pp1, 32);
        if (l4 == 0) {
            partial[par][wv][l15][0] = pp0;
            partial[par][wv][l15][1] = pp1;
        }
    };
    // wave-0 reduce of the PREVIOUS step's partials (off critical path)
    auto reduce_out = [&](int par, int t) {
        int r = lane >> 1, j = lane & 1;
        float s = pb_s[j];
        #pragma unroll
        for (int w8 = 0; w8 < 8; w8++) s += partial[par][w8][r][j];
        out[(size_t)(rowBase + r) * (kTDec * 2) + t * 2 + j] = s;
    };

    // ---- decoder step 1 (unfused weights, input = x[:, -1, :2]) ----
    load_w(1);
    if (tid < 2 * kRows) {
        int r = tid >> 1, j = tid & 1;
        decf[r][0][j] = xs[kTEnc - 1][r][0][j];
        decf[r][1][j] = xs[kTEnc - 1][r][1][j];
    }
    __syncthreads();
    {
        half8 bx = *(const half8*)decXaddr1;
        run_step(bx, cur);
        proj_partial(0);
        __syncthreads();
        cur ^= 1;
    }
    load_w(2);   // fused W~ for steps 2..60

    // ---- decoder steps 2..60: identical to encoder + pipelined projection ----
    for (int t = 1; t < kTDec; t++) {
        if (wv == 0 && lane < 2 * kRows) reduce_out((t - 1) & 1, t - 1);
        half8 bx = *(const half8*)decXaddrN;
        run_step(bx, cur);
        proj_partial(t & 1);
        __syncthreads();
        cur ^= 1;
    }
    if (wv == 0 && lane < 2 * kRows) reduce_out((kTDec - 1) & 1, kTDec - 1);
}

extern "C" void kernel_launch(void* const* d_in, const int* in_sizes, int n_in,
                              void* d_out, int out_size, void* d_ws, size_t ws_size,
                              hipStream_t stream) {
    const float* x      = (const float*)d_in[0];
    const float* encWih = (const float*)d_in[1];
    const float* encWhh = (const float*)d_in[2];
    const float* encbih = (const float*)d_in[3];
    const float* encbhh = (const float*)d_in[4];
    const float* decWih = (const float*)d_in[5];
    const float* decWhh = (const float*)d_in[6];
    const float* decbih = (const float*)d_in[7];
    const float* decbhh = (const float*)d_in[8];
    const float* projW  = (const float*)d_in[9];
    const float* projb  = (const float*)d_in[10];

    _Float16* wfrag = (_Float16*)d_ws;
    float* out = (float*)d_out;

    lstm_prep<<<120, 256, 0, stream>>>(encWhh, encWih, decWhh, decWih,
                                       encbih, encbhh, decbih, decbhh,
                                       projW, projb, wfrag);
    // 512 blocks x 512 threads (8 waves), 16 rows each -> 2 blocks/CU
    lstm_main<<<kBTot / kRows, kThreads, 0, stream>>>(x, wfrag, projW, projb, out);
}